// Round 1
// baseline (958.930 us; speedup 1.0000x reference)
//
#include <hip/hip_runtime.h>
#include <hip/hip_bf16.h>
#include <cstdint>
#include <cstddef>

typedef __bf16 bf16_t;
typedef __bf16 bf16x8 __attribute__((ext_vector_type(8)));
typedef __bf16 bf16x4 __attribute__((ext_vector_type(4)));
typedef float f32x4 __attribute__((ext_vector_type(4)));

// ---------------------------------------------------------------------------
// async global->LDS, 16B per lane. LDS dest is wave-uniform base + lane*16;
// the GLOBAL source address is per-lane (this is what lets us land data in
// MFMA-fragment order while keeping the LDS write linear).
// ---------------------------------------------------------------------------
__device__ __forceinline__ void async16(const void* g, void* l) {
  __builtin_amdgcn_global_load_lds(
      (const __attribute__((address_space(1))) void*)g,
      (__attribute__((address_space(3))) void*)l,
      16, 0, 0);
}

// ---------------------------------------------------------------------------
// fp32 -> bf16 weight conversion, 4 weight matrices in one launch.
// ---------------------------------------------------------------------------
__global__ __launch_bounds__(256) void f2b4(const float* __restrict__ w0,
                                            const float* __restrict__ w1,
                                            const float* __restrict__ w2,
                                            const float* __restrict__ w3,
                                            bf16_t* __restrict__ o0,
                                            bf16_t* __restrict__ o1,
                                            bf16_t* __restrict__ o2,
                                            bf16_t* __restrict__ o3) {
  const float* in = (blockIdx.y == 0) ? w0 : (blockIdx.y == 1) ? w1
                   : (blockIdx.y == 2) ? w2 : w3;
  bf16_t* out = (blockIdx.y == 0) ? o0 : (blockIdx.y == 1) ? o1
               : (blockIdx.y == 2) ? o2 : o3;
  const int i = blockIdx.x * 256 + threadIdx.x;
  float4 v = ((const float4*)in)[i];
  bf16x4 o = { (__bf16)v.x, (__bf16)v.y, (__bf16)v.z, (__bf16)v.w };
  ((bf16x4*)out)[i] = o;
}

// ---------------------------------------------------------------------------
// GroupNorm: x (8,512,4096) fp32 -> ht (8, N, C) bf16 (transposed).
// ---------------------------------------------------------------------------
__global__ __launch_bounds__(256) void groupnorm_t(const float* __restrict__ x,
                                                   const float* __restrict__ gamma,
                                                   const float* __restrict__ beta,
                                                   bf16_t* __restrict__ ht) {
  const int g = blockIdx.x;
  const int b = blockIdx.y;
  const int t = threadIdx.x;
  const float* xg = x + ((size_t)(b * 512 + g * 16)) * 4096;
  const float4* x4 = (const float4*)xg;

  float s = 0.f, ss = 0.f;
  #pragma unroll 8
  for (int i = t; i < 16384; i += 256) {
    float4 v = x4[i];
    s  += (v.x + v.y) + (v.z + v.w);
    ss += (v.x * v.x + v.y * v.y) + (v.z * v.z + v.w * v.w);
  }
  #pragma unroll
  for (int o = 32; o; o >>= 1) { s += __shfl_xor(s, o); ss += __shfl_xor(ss, o); }
  __shared__ float rs[4], rss[4];
  if ((t & 63) == 0) { rs[t >> 6] = s; rss[t >> 6] = ss; }
  __syncthreads();
  const float S  = (rs[0] + rs[1]) + (rs[2] + rs[3]);
  const float SS = (rss[0] + rss[1]) + (rss[2] + rss[3]);
  const float inv_n = 1.0f / 65536.0f;
  const float mean = S * inv_n;
  const float var  = SS * inv_n - mean * mean;
  const float rstd = rsqrtf(var + 1e-5f);

  float ga[16], be[16];
  #pragma unroll
  for (int cc = 0; cc < 16; cc++) {
    const float gm = gamma[g * 16 + cc] * rstd;
    ga[cc] = gm;
    be[cc] = beta[g * 16 + cc] - mean * gm;
  }

  bf16_t* hg = ht + (size_t)b * 4096 * 512 + g * 16;
  for (int n = t; n < 4096; n += 256) {
    bf16_t o[16];
    #pragma unroll
    for (int cc = 0; cc < 16; cc++)
      o[cc] = (bf16_t)(xg[(size_t)cc * 4096 + n] * ga[cc] + be[cc]);
    bf16x8* dst = (bf16x8*)(hg + (size_t)n * 512);
    dst[0] = *(bf16x8*)&o[0];
    dst[1] = *(bf16x8*)&o[8];
  }
}

// ---------------------------------------------------------------------------
// C = A @ B^T  (A: MxK row-major, B: NxK row-major, both bf16 K-contiguous).
// m97 structure, XCD-aware strip swizzle.
// ---------------------------------------------------------------------------
template <int OUTF32, int BIAS_MODE, int RESID, int SWAP>
__global__ __launch_bounds__(256)
void gemm_bt(const bf16_t* __restrict__ A, const bf16_t* __restrict__ B,
             void* __restrict__ Cv, const float* __restrict__ bias,
             const float* __restrict__ resid,
             int TM, int TN, int Z, int K, float scale,
             long sA, long sB, long sC, long sR) {
  __shared__ alignas(16) bf16_t lA[4096];
  __shared__ alignas(16) bf16_t lB[4096];

  const int lid = blockIdx.x;
  const int xcd = lid & 7;
  const int j   = lid >> 3;
  const int sd  = SWAP ? TN : TM;
  const int I   = SWAP ? TM : TN;
  const int spx = (sd * Z) >> 3;
  const int strip = xcd * spx + j / I;
  const int inner = j % I;
  const int z    = strip / sd;
  const int sidx = strip % sd;
  const int bm = (SWAP ? inner : sidx) * 128;
  const int bn = (SWAP ? sidx : inner) * 128;
  const int N = TN * 128;

  const int t = threadIdx.x;
  const int lane = t & 63;
  const int w = t >> 6;
  const int wm = (w >> 1) * 64;
  const int wn = (w & 1) * 64;
  const bf16_t* Ab = A + (size_t)z * (size_t)sA;
  const bf16_t* Bb = B + (size_t)z * (size_t)sB;

  const int lrow = lane >> 2;
  const int lcol = (lane & 3) * 8;
  const int quad = lane >> 4;
  const int l15 = lane & 15;

  const bf16_t* gA0 = Ab + (size_t)(bm + w * 16 + lrow) * K + lcol;
  const bf16_t* gA1 = Ab + (size_t)(bm + (w + 4) * 16 + lrow) * K + lcol;
  const bf16_t* gB0 = Bb + (size_t)(bn + w * 16 + lrow) * K + lcol;
  const bf16_t* gB1 = Bb + (size_t)(bn + (w + 4) * 16 + lrow) * K + lcol;
  bf16_t* lA0 = &lA[w * 512];
  bf16_t* lA1 = &lA[(w + 4) * 512];
  bf16_t* lB0 = &lB[w * 512];
  bf16_t* lB1 = &lB[(w + 4) * 512];

  f32x4 acc[4][4] = {};

  for (int k0 = 0; k0 < K; k0 += 32) {
    __syncthreads();
    async16(gA0 + k0, lA0);
    async16(gA1 + k0, lA1);
    async16(gB0 + k0, lB0);
    async16(gB1 + k0, lB1);
    __syncthreads();

    bf16x8 af[4], bfr[4];
    #pragma unroll
    for (int i = 0; i < 4; i++) {
      af[i]  = *(const bf16x8*)&lA[(wm + i * 16 + l15) * 32 + quad * 8];
      bfr[i] = *(const bf16x8*)&lB[(wn + i * 16 + l15) * 32 + quad * 8];
    }
    #pragma unroll
    for (int i = 0; i < 4; i++)
      #pragma unroll
      for (int jj = 0; jj < 4; jj++)
        acc[i][jj] = __builtin_amdgcn_mfma_f32_16x16x32_bf16(af[i], bfr[jj],
                                                             acc[i][jj], 0, 0, 0);
  }

  float* Cf = (float*)Cv + (size_t)z * (size_t)sC;
  bf16_t* Cb = (bf16_t*)Cv + (size_t)z * (size_t)sC;
  const float* Rb = RESID ? (resid + (size_t)z * (size_t)sR) : nullptr;

  #pragma unroll
  for (int i = 0; i < 4; i++) {
    const int row0 = bm + wm + i * 16 + quad * 4;
    #pragma unroll
    for (int jj = 0; jj < 4; jj++) {
      const int col = bn + wn + jj * 16 + l15;
      #pragma unroll
      for (int r = 0; r < 4; r++) {
        float v = acc[i][jj][r] * scale;
        const int row = row0 + r;
        if (BIAS_MODE == 1) v += bias[row];
        else if (BIAS_MODE == 2) v += bias[col];
        const size_t idx = (size_t)row * N + col;
        if (RESID) v += Rb[idx];
        if (OUTF32) Cf[idx] = v;
        else Cb[idx] = (bf16_t)v;
      }
    }
  }
}

// ---------------------------------------------------------------------------
// Fused attention: O = softmax(scale * Q K^T) V.
// Q,K: (8, 4096, 512) bf16; V: (8, 512, 4096) bf16; O: (8, 4096, 512) bf16.
//
// Round-5 restructure (theory: LDS-BW-bound, 8-way bank conflicts on all
// fragment ds_read_b128, zero stage/compute overlap):
//   1. K/V tiles live in LDS in MFMA-FRAGMENT ORDER: 32 blobs x 1KB per
//      32KB tile; blob (p,n) holds lane L's bf16x8 fragment at byte L*16.
//      The per-lane GLOBAL source address is permuted instead (global
//      address set per async16 is unchanged -> same coalescing), so every
//      fragment read is the canonical linear base+lane*16 -> conflict-free.
//   2. lS (P tile): 256B-stride rows, 16B slots XOR-swizzled by row
//      (phys slot = slot ^ row). Reads ~conflict-free, writes ~4-way.
//   3. Double-buffered tile (2 x 32KB; LDS 80KB total is free since
//      occupancy is grid-limited at 2 blocks/CU): issue next pair's
//      async16s BEFORE computing current pair -> the vmcnt(0) drain at the
//      barrier overlaps with MFMA+ds_read; 8 barriers/chunk instead of 16.
//      Softmax runs before the A->C barrier to hide V-load latency.
//   4. s_setprio(1) around MFMA clusters.
// ---------------------------------------------------------------------------
__global__ __launch_bounds__(256, 2)
void flash_attn(const bf16_t* __restrict__ Qm, const bf16_t* __restrict__ Km,
                const bf16_t* __restrict__ Vm, bf16_t* __restrict__ Om,
                float scale) {
  __shared__ alignas(16) bf16_t lK[2][16384];   // 2 x 32KB tile, fragment order
  __shared__ alignas(16) bf16_t lS[4][2048];    // per-wave P: [16][128], swizzled

  const int bid = blockIdx.x;
  const int z = bid & 7;
  const int qb = bid >> 3;
  const int m0 = qb * 64;

  const int t = threadIdx.x;
  const int lane = t & 63;
  const int w = t >> 6;
  const int quad = lane >> 4;
  const int l15 = lane & 15;

  const size_t sND = 4096ull * 512;
  const bf16_t* q = Qm + z * sND;
  const bf16_t* k = Km + z * sND;
  const bf16_t* v = Vm + z * sND;

  // Per-lane global offsets for fragment-order staging: lane L fetches
  // row (L&15), 8-elem column piece (L>>4) of the blob's 16x32 subtile.
  const int kOffK = l15 * 512 + quad * 8;    // K rows are 512 elems
  const int kOffV = l15 * 4096 + quad * 8;   // V rows are 4096 elems

  // Q fragments: qf[kk] = Q[m0 + w*16 + l15][kk*32 + quad*8 .. +8]
  bf16x8 qf[16];
  {
    const bf16_t* qrow = q + (size_t)(m0 + w * 16 + l15) * 512 + quad * 8;
    #pragma unroll
    for (int kk = 0; kk < 16; kk++)
      qf[kk] = *(const bf16x8*)(qrow + kk * 32);
  }

  f32x4 o_acc[32] = {};               // O[quad*4+r][ idx*16 + l15 ]
  float l_run[4] = {0.f, 0.f, 0.f, 0.f};

  // Prologue: stage K (chunk 0, kd2=0) into buffer 0.
  #pragma unroll
  for (int c = 0; c < 8; c++) {
    const int p = c >> 1, n = (w << 1) | (c & 1);
    async16(k + (size_t)(n * 16) * 512 + p * 32 + kOffK,
            &lK[0][(p * 8 + n) << 9]);
  }
  __syncthreads();

  for (int kc = 0; kc < 4096; kc += 128) {
    f32x4 s_acc[8] = {};
    float lsum[4] = {0.f, 0.f, 0.f, 0.f};

    // ---- Phase A: S = Q @ K_chunk^T (pairs 0..3; compute buf kd2&1) ----
    #pragma unroll
    for (int kd2 = 0; kd2 < 4; kd2++) {
      // prefetch next pair into the other buffer
      if (kd2 < 3) {
        #pragma unroll
        for (int c = 0; c < 8; c++) {
          const int p = c >> 1, n = (w << 1) | (c & 1);
          async16(k + (size_t)(kc + n * 16) * 512 + (kd2 + 1) * 128 + p * 32 + kOffK,
                  &lK[(kd2 + 1) & 1][(p * 8 + n) << 9]);
        }
      } else {
        #pragma unroll
        for (int c = 0; c < 8; c++) {
          const int p = c >> 1, nd = (w << 1) | (c & 1);
          async16(v + (size_t)(nd * 16) * 4096 + kc + p * 32 + kOffV,
                  &lK[(kd2 + 1) & 1][(p * 8 + nd) << 9]);
        }
      }
      const bf16_t* buf = lK[kd2 & 1];
      __builtin_amdgcn_s_setprio(1);
      #pragma unroll
      for (int p = 0; p < 4; p++)
        #pragma unroll
        for (int n = 0; n < 8; n++) {
          bf16x8 kf = *(const bf16x8*)&buf[((p * 8 + n) << 9) + lane * 8];
          s_acc[n] = __builtin_amdgcn_mfma_f32_16x16x32_bf16(
              qf[kd2 * 4 + p], kf, s_acc[n], 0, 0, 0);
        }
      __builtin_amdgcn_s_setprio(0);

      if (kd2 == 3) {
        // ---- Phase B: exp (no max), row-sum, P -> swizzled lS ----
        // (runs before the barrier: hides the in-flight V loads)
        #pragma unroll
        for (int n = 0; n < 8; n++)
          #pragma unroll
          for (int r = 0; r < 4; r++) {
            float e = __expf(s_acc[n][r] * scale);
            lsum[r] += e;
            const int row = quad * 4 + r;
            const int sl = ((n * 2 + (l15 >> 3)) ^ row) & 15;
            lS[w][row * 128 + sl * 8 + (l15 & 7)] = (bf16_t)e;
          }
        #pragma unroll
        for (int r = 0; r < 4; r++) {
          float s = lsum[r];
          s += __shfl_xor(s, 1); s += __shfl_xor(s, 2);
          s += __shfl_xor(s, 4); s += __shfl_xor(s, 8);
          l_run[r] += s;
        }
      }
      __syncthreads();
    }

    // ---- Phase C: O += P @ V_chunk (pairs 4..7; compute buf db&1) ----
    #pragma unroll
    for (int db = 0; db < 4; db++) {
      if (db < 3) {
        #pragma unroll
        for (int c = 0; c < 8; c++) {
          const int p = c >> 1, nd = (w << 1) | (c & 1);
          async16(v + (size_t)((db + 1) * 128 + nd * 16) * 4096 + kc + p * 32 + kOffV,
                  &lK[(db + 1) & 1][(p * 8 + nd) << 9]);
        }
      } else {
        const int kc2 = (kc + 128) & 4095;   // last chunk: harmless wrap, no OOB
        #pragma unroll
        for (int c = 0; c < 8; c++) {
          const int p = c >> 1, n = (w << 1) | (c & 1);
          async16(k + (size_t)(kc2 + n * 16) * 512 + p * 32 + kOffK,
                  &lK[(db + 1) & 1][(p * 8 + n) << 9]);
        }
      }
      const bf16_t* buf = lK[db & 1];
      __builtin_amdgcn_s_setprio(1);
      #pragma unroll
      for (int p = 0; p < 4; p++) {
        bf16x8 af = *(const bf16x8*)
            &lS[w][l15 * 128 + (((p * 4 + quad) ^ l15) & 15) * 8];
        #pragma unroll
        for (int nd = 0; nd < 8; nd++) {
          bf16x8 vf = *(const bf16x8*)&buf[((p * 8 + nd) << 9) + lane * 8];
          o_acc[db * 8 + nd] = __builtin_amdgcn_mfma_f32_16x16x32_bf16(
              af, vf, o_acc[db * 8 + nd], 0, 0, 0);
        }
      }
      __builtin_amdgcn_s_setprio(0);
      __syncthreads();
    }
  }

  // ---- epilogue: divide by row-sum, store bf16 ----
  bf16_t* o = Om + z * sND;
  float rl[4];
  #pragma unroll
  for (int r = 0; r < 4; r++) rl[r] = 1.0f / l_run[r];
  #pragma unroll
  for (int nd = 0; nd < 32; nd++)
    #pragma unroll
    for (int r = 0; r < 4; r++) {
      const int row = m0 + w * 16 + quad * 4 + r;
      const int col = nd * 16 + l15;
      o[(size_t)row * 512 + col] = (bf16_t)(o_acc[nd][r] * rl[r]);
    }
}

// ---------------------------------------------------------------------------
// kernel_launch — all 8 batches per launch, 7 launches, ~130 MB ws
// ---------------------------------------------------------------------------
extern "C" void kernel_launch(void* const* d_in, const int* in_sizes, int n_in,
                              void* d_out, int out_size, void* d_ws, size_t ws_size,
                              hipStream_t stream) {
  const float* x   = (const float*)d_in[0];
  const float* gnw = (const float*)d_in[1];
  const float* gnb = (const float*)d_in[2];
  const float* qw  = (const float*)d_in[3];
  const float* qb  = (const float*)d_in[4];
  const float* kw  = (const float*)d_in[5];
  const float* kb  = (const float*)d_in[6];
  const float* vw  = (const float*)d_in[7];
  const float* vb  = (const float*)d_in[8];
  const float* pw  = (const float*)d_in[9];
  const float* pb  = (const float*)d_in[10];
  float* out = (float*)d_out;

  char* ws = (char*)d_ws;
  size_t off = 0;
  auto alloc = [&](size_t bytes) -> void* {
    void* p = ws + off;
    off += (bytes + 255) & ~(size_t)255;
    return p;
  };

  const long sND = 4096L * 512;

  bf16_t* wqb = (bf16_t*)alloc(512ull * 512 * 2);
  bf16_t* wkb = (bf16_t*)alloc(512ull * 512 * 2);
  bf16_t* wvb = (bf16_t*)alloc(512ull * 512 * 2);
  bf16_t* wpb = (bf16_t*)alloc(512ull * 512 * 2);
  bf16_t* ht  = (bf16_t*)alloc(8ull * 4096 * 512 * 2);   // (8,N,C); aliased by hf
  bf16_t* qbf = (bf16_t*)alloc(8ull * 4096 * 512 * 2);   // (8,N,D)
  bf16_t* kbf = (bf16_t*)alloc(8ull * 4096 * 512 * 2);   // (8,N,D)
  bf16_t* vbf = (bf16_t*)alloc(8ull * 4096 * 512 * 2);   // (8,D,N)
  bf16_t* hfb = ht;  // alias: ht dead after q/k/v GEMMs

  f2b4<<<dim3(256, 4), 256, 0, stream>>>(qw, kw, vw, pw, wqb, wkb, wvb, wpb);
  groupnorm_t<<<dim3(32, 8), 256, 0, stream>>>(x, gnw, gnb, ht);

  // q[n,d] = sum_c ht[n,c]*qw[d,c] + qb[d]
  gemm_bt<0, 2, 0, 0><<<1024, 256, 0, stream>>>(
      ht, wqb, qbf, qb, nullptr, 32, 4, 8, 512, 1.0f, sND, 0, sND, 0);
  gemm_bt<0, 2, 0, 0><<<1024, 256, 0, stream>>>(
      ht, wkb, kbf, kb, nullptr, 32, 4, 8, 512, 1.0f, sND, 0, sND, 0);
  // v[d,n] = sum_c vw[d,c]*ht[n,c] + vb[d]
  gemm_bt<0, 1, 0, 1><<<1024, 256, 0, stream>>>(
      wvb, ht, vbf, vb, nullptr, 4, 32, 8, 512, 1.0f, 0, sND, sND, 0);

  // fused attention (overwrites ht with hf)
  const float scale = 0.044194173824159216f;  // 512^-0.5 (ref scales by C)
  flash_attn<<<512, 256, 0, stream>>>(qbf, kbf, vbf, hfb, scale);

  // out[c,n] = x[c,n] + pb[c] + sum_d pw[c,d]*hf[n,d]
  gemm_bt<1, 1, 1, 1><<<1024, 256, 0, stream>>>(
      wpb, hfb, out, pb, x, 4, 32, 8, 512, 1.0f, 0, sND, 512L * 4096, 512L * 4096);
}

// Round 2
// 890.696 us; speedup vs baseline: 1.0766x; 1.0766x over previous
//
#include <hip/hip_runtime.h>
#include <hip/hip_bf16.h>
#include <cstdint>
#include <cstddef>

typedef __bf16 bf16_t;
typedef __bf16 bf16x8 __attribute__((ext_vector_type(8)));
typedef __bf16 bf16x4 __attribute__((ext_vector_type(4)));
typedef float f32x4 __attribute__((ext_vector_type(4)));

// ---------------------------------------------------------------------------
// async global->LDS, 16B per lane. LDS dest is wave-uniform base + lane*16;
// the GLOBAL source address is per-lane, which lets us land data in
// MFMA-fragment order while keeping the LDS write linear.
// ---------------------------------------------------------------------------
__device__ __forceinline__ void async16(const void* g, void* l) {
  __builtin_amdgcn_global_load_lds(
      (const __attribute__((address_space(1))) void*)g,
      (__attribute__((address_space(3))) void*)l,
      16, 0, 0);
}

// ---------------------------------------------------------------------------
// fp32 -> bf16 weight conversion, 4 weight matrices in one launch.
// ---------------------------------------------------------------------------
__global__ __launch_bounds__(256) void f2b4(const float* __restrict__ w0,
                                            const float* __restrict__ w1,
                                            const float* __restrict__ w2,
                                            const float* __restrict__ w3,
                                            bf16_t* __restrict__ o0,
                                            bf16_t* __restrict__ o1,
                                            bf16_t* __restrict__ o2,
                                            bf16_t* __restrict__ o3) {
  const float* in = (blockIdx.y == 0) ? w0 : (blockIdx.y == 1) ? w1
                   : (blockIdx.y == 2) ? w2 : w3;
  bf16_t* out = (blockIdx.y == 0) ? o0 : (blockIdx.y == 1) ? o1
               : (blockIdx.y == 2) ? o2 : o3;
  const int i = blockIdx.x * 256 + threadIdx.x;
  float4 v = ((const float4*)in)[i];
  bf16x4 o = { (__bf16)v.x, (__bf16)v.y, (__bf16)v.z, (__bf16)v.w };
  ((bf16x4*)out)[i] = o;
}

// ---------------------------------------------------------------------------
// GroupNorm: x (8,512,4096) fp32 -> ht (8, N, C) bf16 (transposed).
// ---------------------------------------------------------------------------
__global__ __launch_bounds__(256) void groupnorm_t(const float* __restrict__ x,
                                                   const float* __restrict__ gamma,
                                                   const float* __restrict__ beta,
                                                   bf16_t* __restrict__ ht) {
  const int g = blockIdx.x;
  const int b = blockIdx.y;
  const int t = threadIdx.x;
  const float* xg = x + ((size_t)(b * 512 + g * 16)) * 4096;
  const float4* x4 = (const float4*)xg;

  float s = 0.f, ss = 0.f;
  #pragma unroll 8
  for (int i = t; i < 16384; i += 256) {
    float4 v = x4[i];
    s  += (v.x + v.y) + (v.z + v.w);
    ss += (v.x * v.x + v.y * v.y) + (v.z * v.z + v.w * v.w);
  }
  #pragma unroll
  for (int o = 32; o; o >>= 1) { s += __shfl_xor(s, o); ss += __shfl_xor(ss, o); }
  __shared__ float rs[4], rss[4];
  if ((t & 63) == 0) { rs[t >> 6] = s; rss[t >> 6] = ss; }
  __syncthreads();
  const float S  = (rs[0] + rs[1]) + (rs[2] + rs[3]);
  const float SS = (rss[0] + rss[1]) + (rss[2] + rss[3]);
  const float inv_n = 1.0f / 65536.0f;
  const float mean = S * inv_n;
  const float var  = SS * inv_n - mean * mean;
  const float rstd = rsqrtf(var + 1e-5f);

  float ga[16], be[16];
  #pragma unroll
  for (int cc = 0; cc < 16; cc++) {
    const float gm = gamma[g * 16 + cc] * rstd;
    ga[cc] = gm;
    be[cc] = beta[g * 16 + cc] - mean * gm;
  }

  bf16_t* hg = ht + (size_t)b * 4096 * 512 + g * 16;
  for (int n = t; n < 4096; n += 256) {
    bf16_t o[16];
    #pragma unroll
    for (int cc = 0; cc < 16; cc++)
      o[cc] = (bf16_t)(xg[(size_t)cc * 4096 + n] * ga[cc] + be[cc]);
    bf16x8* dst = (bf16x8*)(hg + (size_t)n * 512);
    dst[0] = *(bf16x8*)&o[0];
    dst[1] = *(bf16x8*)&o[8];
  }
}

// ---------------------------------------------------------------------------
// C = A @ B^T  (A: MxK row-major, B: NxK row-major, both bf16 K-contiguous).
// m97 structure, XCD-aware strip swizzle.
// ---------------------------------------------------------------------------
template <int OUTF32, int BIAS_MODE, int RESID, int SWAP>
__global__ __launch_bounds__(256)
void gemm_bt(const bf16_t* __restrict__ A, const bf16_t* __restrict__ B,
             void* __restrict__ Cv, const float* __restrict__ bias,
             const float* __restrict__ resid,
             int TM, int TN, int Z, int K, float scale,
             long sA, long sB, long sC, long sR) {
  __shared__ alignas(16) bf16_t lA[4096];
  __shared__ alignas(16) bf16_t lB[4096];

  const int lid = blockIdx.x;
  const int xcd = lid & 7;
  const int j   = lid >> 3;
  const int sd  = SWAP ? TN : TM;
  const int I   = SWAP ? TM : TN;
  const int spx = (sd * Z) >> 3;
  const int strip = xcd * spx + j / I;
  const int inner = j % I;
  const int z    = strip / sd;
  const int sidx = strip % sd;
  const int bm = (SWAP ? inner : sidx) * 128;
  const int bn = (SWAP ? sidx : inner) * 128;
  const int N = TN * 128;

  const int t = threadIdx.x;
  const int lane = t & 63;
  const int w = t >> 6;
  const int wm = (w >> 1) * 64;
  const int wn = (w & 1) * 64;
  const bf16_t* Ab = A + (size_t)z * (size_t)sA;
  const bf16_t* Bb = B + (size_t)z * (size_t)sB;

  const int lrow = lane >> 2;
  const int lcol = (lane & 3) * 8;
  const int quad = lane >> 4;
  const int l15 = lane & 15;

  const bf16_t* gA0 = Ab + (size_t)(bm + w * 16 + lrow) * K + lcol;
  const bf16_t* gA1 = Ab + (size_t)(bm + (w + 4) * 16 + lrow) * K + lcol;
  const bf16_t* gB0 = Bb + (size_t)(bn + w * 16 + lrow) * K + lcol;
  const bf16_t* gB1 = Bb + (size_t)(bn + (w + 4) * 16 + lrow) * K + lcol;
  bf16_t* lA0 = &lA[w * 512];
  bf16_t* lA1 = &lA[(w + 4) * 512];
  bf16_t* lB0 = &lB[w * 512];
  bf16_t* lB1 = &lB[(w + 4) * 512];

  f32x4 acc[4][4] = {};

  for (int k0 = 0; k0 < K; k0 += 32) {
    __syncthreads();
    async16(gA0 + k0, lA0);
    async16(gA1 + k0, lA1);
    async16(gB0 + k0, lB0);
    async16(gB1 + k0, lB1);
    __syncthreads();

    bf16x8 af[4], bfr[4];
    #pragma unroll
    for (int i = 0; i < 4; i++) {
      af[i]  = *(const bf16x8*)&lA[(wm + i * 16 + l15) * 32 + quad * 8];
      bfr[i] = *(const bf16x8*)&lB[(wn + i * 16 + l15) * 32 + quad * 8];
    }
    #pragma unroll
    for (int i = 0; i < 4; i++)
      #pragma unroll
      for (int jj = 0; jj < 4; jj++)
        acc[i][jj] = __builtin_amdgcn_mfma_f32_16x16x32_bf16(af[i], bfr[jj],
                                                             acc[i][jj], 0, 0, 0);
  }

  float* Cf = (float*)Cv + (size_t)z * (size_t)sC;
  bf16_t* Cb = (bf16_t*)Cv + (size_t)z * (size_t)sC;
  const float* Rb = RESID ? (resid + (size_t)z * (size_t)sR) : nullptr;

  #pragma unroll
  for (int i = 0; i < 4; i++) {
    const int row0 = bm + wm + i * 16 + quad * 4;
    #pragma unroll
    for (int jj = 0; jj < 4; jj++) {
      const int col = bn + wn + jj * 16 + l15;
      #pragma unroll
      for (int r = 0; r < 4; r++) {
        float v = acc[i][jj][r] * scale;
        const int row = row0 + r;
        if (BIAS_MODE == 1) v += bias[row];
        else if (BIAS_MODE == 2) v += bias[col];
        const size_t idx = (size_t)row * N + col;
        if (RESID) v += Rb[idx];
        if (OUTF32) Cf[idx] = v;
        else Cb[idx] = (bf16_t)v;
      }
    }
  }
}

// ---------------------------------------------------------------------------
// Fused attention: O = softmax(scale * Q K^T) V.
// Q,K: (8, 4096, 512) bf16; V: (8, 512, 4096) bf16; O: (8, 4096, 512) bf16.
//
// Round-6: round-0's simple sync structure (stage -> barrier -> compute ->
// barrier; no double-buffer, no prefetch-before-compute — round-1 showed
// that restructure regresses: +148 MB HBM writes, +41% time at identical
// MFMA/VALU work) combined with round-1's PROVEN conflict-free LDS layouts
// (SQ_LDS_BANK_CONFLICT 7.13e7 -> 0):
//   1. K/V tile in MFMA-FRAGMENT ORDER: 32 blobs x 1 KB; blob (p,n) holds
//      lane L's bf16x8 fragment at byte L*16. The per-lane GLOBAL source
//      address is permuted instead (address set per async16 unchanged ->
//      same coalescing); every fragment ds_read_b128 is base + lane*16.
//   2. lS (P tile): rows of 128 elems, 16 B slots XOR-swizzled by row.
//   3. s_setprio(1) around MFMA clusters (measured +4-7% on attn).
// ---------------------------------------------------------------------------
__global__ __launch_bounds__(256, 2)
void flash_attn(const bf16_t* __restrict__ Qm, const bf16_t* __restrict__ Km,
                const bf16_t* __restrict__ Vm, bf16_t* __restrict__ Om,
                float scale) {
  __shared__ alignas(16) bf16_t lT[32][512];    // K or V tile, 32 KB, blob order
  __shared__ alignas(16) bf16_t lS[4][2048];    // per-wave P: [16][128], swizzled

  const int bid = blockIdx.x;
  const int z = bid & 7;
  const int qb = bid >> 3;
  const int m0 = qb * 64;

  const int t = threadIdx.x;
  const int lane = t & 63;
  const int w = t >> 6;
  const int quad = lane >> 4;
  const int l15 = lane & 15;

  const size_t sND = 4096ull * 512;
  const bf16_t* q = Qm + z * sND;
  const bf16_t* k = Km + z * sND;
  const bf16_t* v = Vm + z * sND;

  // Per-lane global offsets for fragment-order staging: lane L fetches
  // row (L&15), 8-elem column piece (L>>4) of the blob's 16x32 subtile.
  const int kOffK = l15 * 512 + quad * 8;    // K rows are 512 elems
  const int kOffV = l15 * 4096 + quad * 8;   // V rows are 4096 elems

  // Q fragments: qf[kk] = Q[m0 + w*16 + l15][kk*32 + quad*8 .. +8]
  bf16x8 qf[16];
  {
    const bf16_t* qrow = q + (size_t)(m0 + w * 16 + l15) * 512 + quad * 8;
    #pragma unroll
    for (int kk = 0; kk < 16; kk++)
      qf[kk] = *(const bf16x8*)(qrow + kk * 32);
  }

  f32x4 o_acc[32] = {};               // O[quad*4+r][ idx*16 + l15 ]
  float l_run[4] = {0.f, 0.f, 0.f, 0.f};

  for (int kc = 0; kc < 4096; kc += 128) {
    // ---- Phase A: S = Q @ K_chunk^T. 4 pairs, each stages 128key x 128d ----
    f32x4 s_acc[8] = {};
    #pragma unroll
    for (int kd2 = 0; kd2 < 4; kd2++) {
      __syncthreads();
      #pragma unroll
      for (int c = 0; c < 8; c++) {
        const int p = c >> 1;
        const int n = (w << 1) | (c & 1);
        async16(k + (size_t)(kc + n * 16) * 512 + kd2 * 128 + p * 32 + kOffK,
                &lT[p * 8 + n][0]);
      }
      __syncthreads();
      __builtin_amdgcn_s_setprio(1);
      #pragma unroll
      for (int p = 0; p < 4; p++)
        #pragma unroll
        for (int n = 0; n < 8; n++) {
          bf16x8 kf = *(const bf16x8*)&lT[p * 8 + n][lane * 8];
          s_acc[n] = __builtin_amdgcn_mfma_f32_16x16x32_bf16(
              qf[kd2 * 4 + p], kf, s_acc[n], 0, 0, 0);
        }
      __builtin_amdgcn_s_setprio(0);
    }

    // ---- Phase B: exp (no max), row-sum, P -> swizzled per-wave lS ----
    float lsum[4] = {0.f, 0.f, 0.f, 0.f};
    #pragma unroll
    for (int n = 0; n < 8; n++)
      #pragma unroll
      for (int r = 0; r < 4; r++) {
        float e = __expf(s_acc[n][r] * scale);
        lsum[r] += e;
        const int row = quad * 4 + r;
        const int sl = ((n * 2 + (l15 >> 3)) ^ row) & 15;
        lS[w][row * 128 + sl * 8 + (l15 & 7)] = (bf16_t)e;
      }
    #pragma unroll
    for (int r = 0; r < 4; r++) {
      float s = lsum[r];
      s += __shfl_xor(s, 1); s += __shfl_xor(s, 2);
      s += __shfl_xor(s, 4); s += __shfl_xor(s, 8);
      l_run[r] += s;
    }

    // ---- Phase C: O += P @ V_chunk. 4 pairs, each stages 128d x 128key ----
    #pragma unroll
    for (int db = 0; db < 4; db++) {
      __syncthreads();   // protects lT reuse after phase A / previous db
      #pragma unroll
      for (int c = 0; c < 8; c++) {
        const int p = c >> 1;
        const int nd = (w << 1) | (c & 1);
        async16(v + (size_t)(db * 128 + nd * 16) * 4096 + kc + p * 32 + kOffV,
                &lT[p * 8 + nd][0]);
      }
      __syncthreads();
      __builtin_amdgcn_s_setprio(1);
      #pragma unroll
      for (int p = 0; p < 4; p++) {
        bf16x8 af = *(const bf16x8*)
            &lS[w][l15 * 128 + (((p * 4 + quad) ^ l15) & 15) * 8];
        #pragma unroll
        for (int nd = 0; nd < 8; nd++) {
          bf16x8 vf = *(const bf16x8*)&lT[p * 8 + nd][lane * 8];
          o_acc[db * 8 + nd] = __builtin_amdgcn_mfma_f32_16x16x32_bf16(
              af, vf, o_acc[db * 8 + nd], 0, 0, 0);
        }
      }
      __builtin_amdgcn_s_setprio(0);
    }
  }

  // ---- epilogue: divide by row-sum, store bf16 ----
  bf16_t* o = Om + z * sND;
  float rl[4];
  #pragma unroll
  for (int r = 0; r < 4; r++) rl[r] = 1.0f / l_run[r];
  #pragma unroll
  for (int nd = 0; nd < 32; nd++)
    #pragma unroll
    for (int r = 0; r < 4; r++) {
      const int row = m0 + w * 16 + quad * 4 + r;
      const int col = nd * 16 + l15;
      o[(size_t)row * 512 + col] = (bf16_t)(o_acc[nd][r] * rl[r]);
    }
}

// ---------------------------------------------------------------------------
// kernel_launch — all 8 batches per launch, 7 launches, ~130 MB ws
// ---------------------------------------------------------------------------
extern "C" void kernel_launch(void* const* d_in, const int* in_sizes, int n_in,
                              void* d_out, int out_size, void* d_ws, size_t ws_size,
                              hipStream_t stream) {
  const float* x   = (const float*)d_in[0];
  const float* gnw = (const float*)d_in[1];
  const float* gnb = (const float*)d_in[2];
  const float* qw  = (const float*)d_in[3];
  const float* qb  = (const float*)d_in[4];
  const float* kw  = (const float*)d_in[5];
  const float* kb  = (const float*)d_in[6];
  const float* vw  = (const float*)d_in[7];
  const float* vb  = (const float*)d_in[8];
  const float* pw  = (const float*)d_in[9];
  const float* pb  = (const float*)d_in[10];
  float* out = (float*)d_out;

  char* ws = (char*)d_ws;
  size_t off = 0;
  auto alloc = [&](size_t bytes) -> void* {
    void* p = ws + off;
    off += (bytes + 255) & ~(size_t)255;
    return p;
  };

  const long sND = 4096L * 512;

  bf16_t* wqb = (bf16_t*)alloc(512ull * 512 * 2);
  bf16_t* wkb = (bf16_t*)alloc(512ull * 512 * 2);
  bf16_t* wvb = (bf16_t*)alloc(512ull * 512 * 2);
  bf16_t* wpb = (bf16_t*)alloc(512ull * 512 * 2);
  bf16_t* ht  = (bf16_t*)alloc(8ull * 4096 * 512 * 2);   // (8,N,C); aliased by hf
  bf16_t* qbf = (bf16_t*)alloc(8ull * 4096 * 512 * 2);   // (8,N,D)
  bf16_t* kbf = (bf16_t*)alloc(8ull * 4096 * 512 * 2);   // (8,N,D)
  bf16_t* vbf = (bf16_t*)alloc(8ull * 4096 * 512 * 2);   // (8,D,N)
  bf16_t* hfb = ht;  // alias: ht dead after q/k/v GEMMs

  f2b4<<<dim3(256, 4), 256, 0, stream>>>(qw, kw, vw, pw, wqb, wkb, wvb, wpb);
  groupnorm_t<<<dim3(32, 8), 256, 0, stream>>>(x, gnw, gnb, ht);

  // q[n,d] = sum_c ht[n,c]*qw[d,c] + qb[d]
  gemm_bt<0, 2, 0, 0><<<1024, 256, 0, stream>>>(
      ht, wqb, qbf, qb, nullptr, 32, 4, 8, 512, 1.0f, sND, 0, sND, 0);
  gemm_bt<0, 2, 0, 0><<<1024, 256, 0, stream>>>(
      ht, wkb, kbf, kb, nullptr, 32, 4, 8, 512, 1.0f, sND, 0, sND, 0);
  // v[d,n] = sum_c vw[d,c]*ht[n,c] + vb[d]
  gemm_bt<0, 1, 0, 1><<<1024, 256, 0, stream>>>(
      wvb, ht, vbf, vb, nullptr, 4, 32, 8, 512, 1.0f, 0, sND, sND, 0);

  // fused attention (overwrites ht with hf)
  const float scale = 0.044194173824159216f;  // 512^-0.5 (ref scales by C)
  flash_attn<<<512, 256, 0, stream>>>(qbf, kbf, vbf, hfb, scale);

  // out[c,n] = x[c,n] + pb[c] + sum_d pw[c,d]*hf[n,d]
  gemm_bt<1, 1, 1, 1><<<1024, 256, 0, stream>>>(
      wpb, hfb, out, pb, x, 4, 32, 8, 512, 1.0f, 0, sND, 512L * 4096, 512L * 4096);
}

// Round 3
// 701.814 us; speedup vs baseline: 1.3664x; 1.2691x over previous
//
#include <hip/hip_runtime.h>
#include <hip/hip_bf16.h>
#include <cstdint>
#include <cstddef>

typedef __bf16 bf16_t;
typedef __bf16 bf16x8 __attribute__((ext_vector_type(8)));
typedef __bf16 bf16x4 __attribute__((ext_vector_type(4)));
typedef float f32x4 __attribute__((ext_vector_type(4)));

// ---------------------------------------------------------------------------
// async global->LDS, 16B per lane. LDS dest is wave-uniform base + lane*16;
// the GLOBAL source address is per-lane.
// ---------------------------------------------------------------------------
__device__ __forceinline__ void async16(const void* g, void* l) {
  __builtin_amdgcn_global_load_lds(
      (const __attribute__((address_space(1))) void*)g,
      (__attribute__((address_space(3))) void*)l,
      16, 0, 0);
}

// ---------------------------------------------------------------------------
// fp32 -> bf16 weight conversion, 4 weight matrices in one launch.
// ---------------------------------------------------------------------------
__global__ __launch_bounds__(256) void f2b4(const float* __restrict__ w0,
                                            const float* __restrict__ w1,
                                            const float* __restrict__ w2,
                                            const float* __restrict__ w3,
                                            bf16_t* __restrict__ o0,
                                            bf16_t* __restrict__ o1,
                                            bf16_t* __restrict__ o2,
                                            bf16_t* __restrict__ o3) {
  const float* in = (blockIdx.y == 0) ? w0 : (blockIdx.y == 1) ? w1
                   : (blockIdx.y == 2) ? w2 : w3;
  bf16_t* out = (blockIdx.y == 0) ? o0 : (blockIdx.y == 1) ? o1
               : (blockIdx.y == 2) ? o2 : o3;
  const int i = blockIdx.x * 256 + threadIdx.x;
  float4 v = ((const float4*)in)[i];
  bf16x4 o = { (__bf16)v.x, (__bf16)v.y, (__bf16)v.z, (__bf16)v.w };
  ((bf16x4*)out)[i] = o;
}

// ---------------------------------------------------------------------------
// GroupNorm: x (8,512,4096) fp32 -> ht (8, N, C) bf16 (transposed).
// ---------------------------------------------------------------------------
__global__ __launch_bounds__(256) void groupnorm_t(const float* __restrict__ x,
                                                   const float* __restrict__ gamma,
                                                   const float* __restrict__ beta,
                                                   bf16_t* __restrict__ ht) {
  const int g = blockIdx.x;
  const int b = blockIdx.y;
  const int t = threadIdx.x;
  const float* xg = x + ((size_t)(b * 512 + g * 16)) * 4096;
  const float4* x4 = (const float4*)xg;

  float s = 0.f, ss = 0.f;
  #pragma unroll 8
  for (int i = t; i < 16384; i += 256) {
    float4 v = x4[i];
    s  += (v.x + v.y) + (v.z + v.w);
    ss += (v.x * v.x + v.y * v.y) + (v.z * v.z + v.w * v.w);
  }
  #pragma unroll
  for (int o = 32; o; o >>= 1) { s += __shfl_xor(s, o); ss += __shfl_xor(ss, o); }
  __shared__ float rs[4], rss[4];
  if ((t & 63) == 0) { rs[t >> 6] = s; rss[t >> 6] = ss; }
  __syncthreads();
  const float S  = (rs[0] + rs[1]) + (rs[2] + rs[3]);
  const float SS = (rss[0] + rss[1]) + (rss[2] + rss[3]);
  const float inv_n = 1.0f / 65536.0f;
  const float mean = S * inv_n;
  const float var  = SS * inv_n - mean * mean;
  const float rstd = rsqrtf(var + 1e-5f);

  float ga[16], be[16];
  #pragma unroll
  for (int cc = 0; cc < 16; cc++) {
    const float gm = gamma[g * 16 + cc] * rstd;
    ga[cc] = gm;
    be[cc] = beta[g * 16 + cc] - mean * gm;
  }

  bf16_t* hg = ht + (size_t)b * 4096 * 512 + g * 16;
  for (int n = t; n < 4096; n += 256) {
    bf16_t o[16];
    #pragma unroll
    for (int cc = 0; cc < 16; cc++)
      o[cc] = (bf16_t)(xg[(size_t)cc * 4096 + n] * ga[cc] + be[cc]);
    bf16x8* dst = (bf16x8*)(hg + (size_t)n * 512);
    dst[0] = *(bf16x8*)&o[0];
    dst[1] = *(bf16x8*)&o[8];
  }
}

// ---------------------------------------------------------------------------
// C = A @ B^T  (A: MxK row-major, B: NxK row-major, both bf16 K-contiguous).
// m97 structure, XCD-aware strip swizzle.
// ---------------------------------------------------------------------------
template <int OUTF32, int BIAS_MODE, int RESID, int SWAP>
__global__ __launch_bounds__(256)
void gemm_bt(const bf16_t* __restrict__ A, const bf16_t* __restrict__ B,
             void* __restrict__ Cv, const float* __restrict__ bias,
             const float* __restrict__ resid,
             int TM, int TN, int Z, int K, float scale,
             long sA, long sB, long sC, long sR) {
  __shared__ alignas(16) bf16_t lA[4096];
  __shared__ alignas(16) bf16_t lB[4096];

  const int lid = blockIdx.x;
  const int xcd = lid & 7;
  const int j   = lid >> 3;
  const int sd  = SWAP ? TN : TM;
  const int I   = SWAP ? TM : TN;
  const int spx = (sd * Z) >> 3;
  const int strip = xcd * spx + j / I;
  const int inner = j % I;
  const int z    = strip / sd;
  const int sidx = strip % sd;
  const int bm = (SWAP ? inner : sidx) * 128;
  const int bn = (SWAP ? sidx : inner) * 128;
  const int N = TN * 128;

  const int t = threadIdx.x;
  const int lane = t & 63;
  const int w = t >> 6;
  const int wm = (w >> 1) * 64;
  const int wn = (w & 1) * 64;
  const bf16_t* Ab = A + (size_t)z * (size_t)sA;
  const bf16_t* Bb = B + (size_t)z * (size_t)sB;

  const int lrow = lane >> 2;
  const int lcol = (lane & 3) * 8;
  const int quad = lane >> 4;
  const int l15 = lane & 15;

  const bf16_t* gA0 = Ab + (size_t)(bm + w * 16 + lrow) * K + lcol;
  const bf16_t* gA1 = Ab + (size_t)(bm + (w + 4) * 16 + lrow) * K + lcol;
  const bf16_t* gB0 = Bb + (size_t)(bn + w * 16 + lrow) * K + lcol;
  const bf16_t* gB1 = Bb + (size_t)(bn + (w + 4) * 16 + lrow) * K + lcol;
  bf16_t* lA0 = &lA[w * 512];
  bf16_t* lA1 = &lA[(w + 4) * 512];
  bf16_t* lB0 = &lB[w * 512];
  bf16_t* lB1 = &lB[(w + 4) * 512];

  f32x4 acc[4][4] = {};

  for (int k0 = 0; k0 < K; k0 += 32) {
    __syncthreads();
    async16(gA0 + k0, lA0);
    async16(gA1 + k0, lA1);
    async16(gB0 + k0, lB0);
    async16(gB1 + k0, lB1);
    __syncthreads();

    bf16x8 af[4], bfr[4];
    #pragma unroll
    for (int i = 0; i < 4; i++) {
      af[i]  = *(const bf16x8*)&lA[(wm + i * 16 + l15) * 32 + quad * 8];
      bfr[i] = *(const bf16x8*)&lB[(wn + i * 16 + l15) * 32 + quad * 8];
    }
    #pragma unroll
    for (int i = 0; i < 4; i++)
      #pragma unroll
      for (int jj = 0; jj < 4; jj++)
        acc[i][jj] = __builtin_amdgcn_mfma_f32_16x16x32_bf16(af[i], bfr[jj],
                                                             acc[i][jj], 0, 0, 0);
  }

  float* Cf = (float*)Cv + (size_t)z * (size_t)sC;
  bf16_t* Cb = (bf16_t*)Cv + (size_t)z * (size_t)sC;
  const float* Rb = RESID ? (resid + (size_t)z * (size_t)sR) : nullptr;

  #pragma unroll
  for (int i = 0; i < 4; i++) {
    const int row0 = bm + wm + i * 16 + quad * 4;
    #pragma unroll
    for (int jj = 0; jj < 4; jj++) {
      const int col = bn + wn + jj * 16 + l15;
      #pragma unroll
      for (int r = 0; r < 4; r++) {
        float v = acc[i][jj][r] * scale;
        const int row = row0 + r;
        if (BIAS_MODE == 1) v += bias[row];
        else if (BIAS_MODE == 2) v += bias[col];
        const size_t idx = (size_t)row * N + col;
        if (RESID) v += Rb[idx];
        if (OUTF32) Cf[idx] = v;
        else Cb[idx] = (bf16_t)v;
      }
    }
  }
}

// ---------------------------------------------------------------------------
// Fused attention: O = softmax(scale * Q K^T) V.
// Q,K: (8, 4096, 512) bf16; V: (8, 512, 4096) bf16; O: (8, 4096, 512) bf16.
//
// Round-7: r0's PROVEN layouts and access patterns verbatim (the [128][32]
// panel tile, srow/scol staging, [16][144] lS — r2's "conflict-free" blob
// layout measured 145 us SLOWER at identical work; the conflict counter is
// benign for b128 wave-reads). Structural changes only:
//   * 8-wave / 512-thread blocks covering 128 q-rows (grid 256 = 1 block/CU,
//     still 2 waves/SIMD; per-wave register profile identical to r0).
//   * 2-phase pipeline at pair granularity (catalog T3-minimum): issue next
//     pair's async16 into tile buffer ^1 BEFORE computing current pair from
//     buffer; ONE __syncthreads per pair (8 barriers/chunk vs 16). The
//     vmcnt(0) drain at the barrier now happens AFTER ~32 MFMA + 32 ds_read
//     of compute -> load latency hidden.
//   * All buffer indices compile-time constants (8 pairs/chunk -> parity
//     repeats every chunk). lS is per-wave private (written phase B, read
//     phase C by the same wave) -> needs no barrier protection.
//   * No setprio (r0 had none; lockstep barriers = m190's null regime).
// Tripwire: if WRITE_SIZE balloons vs ~47 MB, this schedule spills (r1's
// unexplained +137 MB would be explained) -> revert.
// ---------------------------------------------------------------------------
__global__ __launch_bounds__(512, 2)
void flash_attn(const bf16_t* __restrict__ Qm, const bf16_t* __restrict__ Km,
                const bf16_t* __restrict__ Vm, bf16_t* __restrict__ Om,
                float scale) {
  __shared__ alignas(16) bf16_t lT[2][4][128][32];  // 2 x 32 KB tile (K or V)
  __shared__ alignas(16) bf16_t lS[8][16][144];     // per-wave P, 36 KB

  const int bid = blockIdx.x;
  const int z = bid & 7;
  const int qb = bid >> 3;
  const int m0 = qb * 128;

  const int t = threadIdx.x;
  const int lane = t & 63;
  const int w = t >> 6;                 // 0..7
  const int quad = lane >> 4;
  const int l15 = lane & 15;
  const int srow = lane >> 2;           // 16 rows per async16 (64 B rows)
  const int scol = (lane & 3) * 8;      // elems within 32-elem row

  const size_t sND = 4096ull * 512;
  const bf16_t* q = Qm + z * sND;
  const bf16_t* k = Km + z * sND;
  const bf16_t* v = Vm + z * sND;

  // Per-thread staging base pointers (row block w*16 of each panel).
  const bf16_t* kStage = k + (size_t)(w * 16 + srow) * 512 + scol;
  const bf16_t* vStage = v + (size_t)(w * 16 + srow) * 4096 + scol;

  // Q fragments: qf[kk] = Q[m0 + w*16 + l15][kk*32 + quad*8 .. +8]
  bf16x8 qf[16];
  {
    const bf16_t* qrow = q + (size_t)(m0 + w * 16 + l15) * 512 + quad * 8;
    #pragma unroll
    for (int kk = 0; kk < 16; kk++)
      qf[kk] = *(const bf16x8*)(qrow + kk * 32);
  }

  f32x4 o_acc[32] = {};               // O[quad*4+r][ idx*16 + l15 ]
  float l_run[4] = {0.f, 0.f, 0.f, 0.f};
  f32x4 s_acc[8];

  // stage K pair kd2 of chunk kcc into buffer BUF
  auto stageA = [&](int BUF, int kcc, int kd2) __attribute__((always_inline)) {
    #pragma unroll
    for (int c = 0; c < 4; c++)
      async16(kStage + (size_t)kcc * 512 + kd2 * 128 + c * 32,
              &lT[BUF][c][w * 16][0]);
  };
  // stage V pair db of chunk kcc into buffer BUF
  auto stageC = [&](int BUF, int kcc, int db) __attribute__((always_inline)) {
    #pragma unroll
    for (int c = 0; c < 4; c++)
      async16(vStage + (size_t)db * 128 * 4096 + kcc + c * 32,
              &lT[BUF][c][w * 16][0]);
  };
  // S += Q_frag(kd2) @ K_pair^T from buffer BUF   (r0 access pattern)
  auto computeA = [&](int BUF, int kd2) __attribute__((always_inline)) {
    #pragma unroll
    for (int p = 0; p < 4; p++)
      #pragma unroll
      for (int n = 0; n < 8; n++) {
        bf16x8 kf = *(const bf16x8*)&lT[BUF][p][n * 16 + l15][quad * 8];
        s_acc[n] = __builtin_amdgcn_mfma_f32_16x16x32_bf16(
            qf[kd2 * 4 + p], kf, s_acc[n], 0, 0, 0);
      }
  };
  // O(db) += P @ V_pair from buffer BUF   (r0 access pattern)
  auto computeC = [&](int BUF, int db) __attribute__((always_inline)) {
    #pragma unroll
    for (int p = 0; p < 4; p++) {
      bf16x8 af = *(const bf16x8*)&lS[w][l15][p * 32 + quad * 8];
      #pragma unroll
      for (int nd = 0; nd < 8; nd++) {
        bf16x8 vf = *(const bf16x8*)&lT[BUF][p][nd * 16 + l15][quad * 8];
        o_acc[db * 8 + nd] = __builtin_amdgcn_mfma_f32_16x16x32_bf16(
            af, vf, o_acc[db * 8 + nd], 0, 0, 0);
      }
    }
  };
  // exp (no max; |s*scale| small), row-sum, P -> per-wave lS (r0 layout)
  auto phaseB = [&]() __attribute__((always_inline)) {
    float lsum[4] = {0.f, 0.f, 0.f, 0.f};
    #pragma unroll
    for (int n = 0; n < 8; n++)
      #pragma unroll
      for (int r = 0; r < 4; r++) {
        float e = __expf(s_acc[n][r] * scale);
        lsum[r] += e;
        lS[w][quad * 4 + r][n * 16 + l15] = (bf16_t)e;
      }
    #pragma unroll
    for (int r = 0; r < 4; r++) {
      float s = lsum[r];
      s += __shfl_xor(s, 1); s += __shfl_xor(s, 2);
      s += __shfl_xor(s, 4); s += __shfl_xor(s, 8);
      l_run[r] += s;
    }
  };

  // Prologue: stage chunk 0's first K pair into buffer 0.
  stageA(0, 0, 0);
  __syncthreads();

  for (int kc = 0; kc < 4096; kc += 128) {
    #pragma unroll
    for (int n = 0; n < 8; n++) s_acc[n] = (f32x4){0.f, 0.f, 0.f, 0.f};

    // ---- 8 pairs per chunk; stage next pair, compute current, barrier ----
    stageA(1, kc, 1);  computeA(0, 0);            __syncthreads();
    stageA(0, kc, 2);  computeA(1, 1);            __syncthreads();
    stageA(1, kc, 3);  computeA(0, 2);            __syncthreads();
    stageC(0, kc, 0);  computeA(1, 3);  phaseB(); __syncthreads();
    stageC(1, kc, 1);  computeC(0, 0);            __syncthreads();
    stageC(0, kc, 2);  computeC(1, 1);            __syncthreads();
    stageC(1, kc, 3);  computeC(0, 2);            __syncthreads();
    if (kc + 128 < 4096) stageA(0, kc + 128, 0);
    computeC(1, 3);                               __syncthreads();
  }

  // ---- epilogue: divide by row-sum, store bf16 ----
  bf16_t* o = Om + z * sND;
  float rl[4];
  #pragma unroll
  for (int r = 0; r < 4; r++) rl[r] = 1.0f / l_run[r];
  #pragma unroll
  for (int nd = 0; nd < 32; nd++)
    #pragma unroll
    for (int r = 0; r < 4; r++) {
      const int row = m0 + w * 16 + quad * 4 + r;
      const int col = nd * 16 + l15;
      o[(size_t)row * 512 + col] = (bf16_t)(o_acc[nd][r] * rl[r]);
    }
}

// ---------------------------------------------------------------------------
// kernel_launch — all 8 batches per launch, 7 launches, ~130 MB ws
// ---------------------------------------------------------------------------
extern "C" void kernel_launch(void* const* d_in, const int* in_sizes, int n_in,
                              void* d_out, int out_size, void* d_ws, size_t ws_size,
                              hipStream_t stream) {
  const float* x   = (const float*)d_in[0];
  const float* gnw = (const float*)d_in[1];
  const float* gnb = (const float*)d_in[2];
  const float* qw  = (const float*)d_in[3];
  const float* qb  = (const float*)d_in[4];
  const float* kw  = (const float*)d_in[5];
  const float* kb  = (const float*)d_in[6];
  const float* vw  = (const float*)d_in[7];
  const float* vb  = (const float*)d_in[8];
  const float* pw  = (const float*)d_in[9];
  const float* pb  = (const float*)d_in[10];
  float* out = (float*)d_out;

  char* ws = (char*)d_ws;
  size_t off = 0;
  auto alloc = [&](size_t bytes) -> void* {
    void* p = ws + off;
    off += (bytes + 255) & ~(size_t)255;
    return p;
  };

  const long sND = 4096L * 512;

  bf16_t* wqb = (bf16_t*)alloc(512ull * 512 * 2);
  bf16_t* wkb = (bf16_t*)alloc(512ull * 512 * 2);
  bf16_t* wvb = (bf16_t*)alloc(512ull * 512 * 2);
  bf16_t* wpb = (bf16_t*)alloc(512ull * 512 * 2);
  bf16_t* ht  = (bf16_t*)alloc(8ull * 4096 * 512 * 2);   // (8,N,C); aliased by hf
  bf16_t* qbf = (bf16_t*)alloc(8ull * 4096 * 512 * 2);   // (8,N,D)
  bf16_t* kbf = (bf16_t*)alloc(8ull * 4096 * 512 * 2);   // (8,N,D)
  bf16_t* vbf = (bf16_t*)alloc(8ull * 4096 * 512 * 2);   // (8,D,N)
  bf16_t* hfb = ht;  // alias: ht dead after q/k/v GEMMs

  f2b4<<<dim3(256, 4), 256, 0, stream>>>(qw, kw, vw, pw, wqb, wkb, wvb, wpb);
  groupnorm_t<<<dim3(32, 8), 256, 0, stream>>>(x, gnw, gnb, ht);

  // q[n,d] = sum_c ht[n,c]*qw[d,c] + qb[d]
  gemm_bt<0, 2, 0, 0><<<1024, 256, 0, stream>>>(
      ht, wqb, qbf, qb, nullptr, 32, 4, 8, 512, 1.0f, sND, 0, sND, 0);
  gemm_bt<0, 2, 0, 0><<<1024, 256, 0, stream>>>(
      ht, wkb, kbf, kb, nullptr, 32, 4, 8, 512, 1.0f, sND, 0, sND, 0);
  // v[d,n] = sum_c vw[d,c]*ht[n,c] + vb[d]
  gemm_bt<0, 1, 0, 1><<<1024, 256, 0, stream>>>(
      wvb, ht, vbf, vb, nullptr, 4, 32, 8, 512, 1.0f, 0, sND, sND, 0);

  // fused attention (overwrites ht with hf)
  const float scale = 0.044194173824159216f;  // 512^-0.5 (ref scales by C)
  flash_attn<<<256, 512, 0, stream>>>(qbf, kbf, vbf, hfb, scale);

  // out[c,n] = x[c,n] + pb[c] + sum_d pw[c,d]*hf[n,d]
  gemm_bt<1, 1, 1, 1><<<1024, 256, 0, stream>>>(
      wpb, hfb, out, pb, x, 4, 32, 8, 512, 1.0f, 0, sND, 512L * 4096, 512L * 4096);
}